// Round 15
// baseline (421.277 us; speedup 1.0000x reference)
//
#include <hip/hip_runtime.h>

typedef unsigned short u16;
typedef unsigned int   u32;

// RESOLVED (rounds 0-10): d_out is FLOAT32. Inputs f32. din=128, hd=128
// (H=2, dout=64), N=in_sizes[0]/128, NE=in_sizes[1]/2.
// Outputs flat f32: H_out [0,N*64) ; E [N*64,+2NE) ; attr [+NE).
// R17: fp16 (absmax .0156). R22: total-kernel_sum ~65us fixed -> launches
//      ~free. R23 (BEST 210): fused k_work 82 + k_edge 58.
// R25/R26: b%8 XCD partition NULL (scatter still ~55-60; total 233).
//      Mechanism refined: bucket WRITE 54.7MB vs 12.8MB dirty data, bucket
//      is tiny per XCD -> not capacity. Plain stores cache in the ISSUING
//      XCD's L2 -> same line dirtied in ~6 L2s -> ~5x writeback multiply.
//      b%8 block->XCD assumption unverified; if mapping is chunked the
//      partition was void -> null result explained.
// R27: TRUE XCD affinity via s_getreg(HW_REG_XCC_ID) (m09-verified).
//      8 per-segment chunk queues; blocks prefer own XCD's queue, fall
//      back to others when drained (coverage guaranteed regardless of
//      mapping). Passthrough = post-queue streaming work in same kernel.
//      If scatter still >=55us -> ownership theory dead, revert to R23.

#define DIN   128
#define DOUT  64
#define HD    128   // H * DOUT
#define BCAP  64    // bucket capacity per node
#define CH    4096  // edges per work chunk

typedef __attribute__((ext_vector_type(8))) _Float16 f16x8;
typedef __attribute__((ext_vector_type(2))) _Float16 h2;
typedef __attribute__((ext_vector_type(4))) float    f32x4;

union H2U { u32 u; h2 h; };
__device__ __forceinline__ h2  U2H(u32 u) { H2U x; x.u = u; return x.h; }
__device__ __forceinline__ u32 H2Ub(h2 h) { H2U x; x.h = h; return x.u; }

__device__ __forceinline__ u16 f2h(float f) {
    _Float16 h = (_Float16)f;              // RNE
    u16 r; __builtin_memcpy(&r, &h, 2); return r;
}

// packed fp16 max via ISA (v_pk_max_f16 is VOP3P, present on gfx950)
__device__ __forceinline__ u32 pkmax(u32 a, u32 b) {
    u32 d;
    asm("v_pk_max_f16 %0, %1, %2" : "=v"(d) : "v"(a), "v"(b));
    return d;
}

__device__ __forceinline__ float fdot2f(h2 a, h2 b, float c) {
#if __has_builtin(__builtin_amdgcn_fdot2)
    return __builtin_amdgcn_fdot2(a, b, c, false);
#else
    return c + (float)a[0] * (float)b[0] + (float)a[1] * (float)b[1];
#endif
}

// HW_REG_XCC_ID = id 20; simm16 = (size-1)<<11 | offset<<6 | id, size=8
__device__ __forceinline__ u32 my_xcc() {
#if __has_builtin(__builtin_amdgcn_s_getreg)
    return __builtin_amdgcn_s_getreg((7u << 11) | 20u) & 7u;
#else
    return 0u;
#endif
}

// ---------------------------------------------------------------------------
// K0: k_prep = zero count + queues + WT l/r transpose->fp16 + Wfp pack.
// ---------------------------------------------------------------------------
__global__ void k_prep(const float* __restrict__ Wl, const float* __restrict__ Wr,
                       const float* __restrict__ Wf,
                       u16* __restrict__ WTl, u16* __restrict__ WTr,
                       uint4* __restrict__ Wfp, int* __restrict__ count,
                       int* __restrict__ q, int N)
{
    int i = blockIdx.x * 256 + threadIdx.x;
    if (i < N) { count[i] = 0; return; }
    int j = i - N;
    if (j < 16384) {                       // WTl: [c*128+k] = f16(Wl[k*128+c])
        int k = j >> 7, c = j & 127;
        WTl[c * 128 + k] = f2h(Wl[j]);
    } else if (j < 32768) {                // WTr
        int t = j - 16384;
        int k = t >> 7, c = t & 127;
        WTr[c * 128 + k] = f2h(Wr[t]);
    } else if (j < 33792) {                // Wfp (1024 uint4)
        int t = j - 32768;
        int k4 = t >> 5, c = t & 31;
        const float* wrow = Wf + (size_t)(4 * k4) * DOUT;
        u32 a0 = (u32)f2h(wrow[c])              | ((u32)f2h(wrow[DOUT + c]) << 16);
        u32 a1 = (u32)f2h(wrow[2 * DOUT + c])   | ((u32)f2h(wrow[3 * DOUT + c]) << 16);
        u32 a2 = (u32)f2h(wrow[c + 32])         | ((u32)f2h(wrow[DOUT + c + 32]) << 16);
        u32 a3 = (u32)f2h(wrow[2 * DOUT + c + 32]) | ((u32)f2h(wrow[3 * DOUT + c + 32]) << 16);
        Wfp[t] = make_uint4(a0, a1, a2, a3);
    } else if (j < 33800) {                // 8 chunk queues
        q[j - 33792] = 0;
    }
}

// ---------------------------------------------------------------------------
// K1: k_scatter_xq — XCD-affine queued bucket scatter + passthrough.
// Segment s = dst range [s*N/8,(s+1)*N/8). Block reads its TRUE XCD id and
// drains queue q[xcc] first (chunks of CH edges, filtered to segment xcc:
// all bucket/count lines of that segment dirtied by ONE XCD's L2s), then
// falls back to the other queues (coverage guaranteed for any mapping).
// After queues drain: E/attr passthrough slice (streaming).
// ---------------------------------------------------------------------------
__global__ __launch_bounds__(256) void k_scatter_xq(
    const int* __restrict__ E, const float* __restrict__ attr,
    int* __restrict__ count, u16* __restrict__ bucket, int* __restrict__ q,
    float* __restrict__ out, int N, int NE)
{
    __shared__ int sc;
    const int tid = threadIdx.x;
    const int nch = (NE + CH - 1) / CH;
    const u32 xcc = my_xcc();

    for (int pass = 0; pass < 8; pass++) {
        const int s  = (int)((xcc + pass) & 7u);
        const int lo = (int)((long long)s       * N >> 3);
        const int hi = (int)((long long)(s + 1) * N >> 3);
        for (;;) {
            if (tid == 0) sc = atomicAdd(&q[s], 1);
            __syncthreads();
            const int c = sc;
            __syncthreads();
            if (c >= nch) break;
            const int e_end = min(NE, (c + 1) * CH);
            for (int e = c * CH + tid; e < e_end; e += 256) {
                int dst = E[NE + e];
                if ((u32)dst >= (u32)N) dst = 0;
                if (dst < lo || dst >= hi) continue;
                int src = E[e];
                if ((u32)src >= (u32)N) src = 0;
                int rank = atomicAdd(&count[dst], 1);
                if (rank < BCAP) bucket[(size_t)dst * BCAP + rank] = (u16)src;
            }
        }
    }

    // passthrough slice (streaming)
    const size_t base = (size_t)N * DOUT;
    const long long P = 3LL * NE;
    const int nB = gridDim.x;
    int p0 = (int)(((long long)blockIdx.x) * P / nB);
    int p1 = (int)(((long long)blockIdx.x + 1) * P / nB);
    for (int p = p0 + tid; p < p1; p += 256) {
        if (p < 2 * NE) out[base + p] = (float)E[p];
        else            out[base + p] = attr[p - 2 * NE];
    }
}

// ---------------------------------------------------------------------------
// K2: gemm1 — X staged ONCE, both heads computed per block (cb loop).
// dst = f16(X @ W + b), dst[node*128+c]; A = W^T from GLOBAL (32KB, L1-hot),
// B = X fragments held in registers across the cb loop.
// D: col(lane&15)=node, row(quad*4+r)=c -> packed uint2 stores.
// ---------------------------------------------------------------------------
__global__ __launch_bounds__(256) void gemm1(
    const float* __restrict__ X,
    const u16* __restrict__ WTl, const float* __restrict__ bl,
    const u16* __restrict__ WTr, const float* __restrict__ br,
    u16* __restrict__ xl_p, u16* __restrict__ xr_p, int N)
{
    __shared__ u16 sX[64 * 136];    // 17408 B — only LDS

    const int tid  = threadIdx.x;
    const int row0 = blockIdx.x * 64;

    for (int idx = tid; idx < 64 * 32; idx += 256) {
        int r  = idx >> 5;
        int k4 = (idx & 31) << 2;
        int gr = row0 + r;
        float4 v = make_float4(0.f, 0.f, 0.f, 0.f);
        if (gr < N) v = *(const float4*)(X + (size_t)gr * DIN + k4);
        u32 p0 = (u32)f2h(v.x) | ((u32)f2h(v.y) << 16);
        u32 p1 = (u32)f2h(v.z) | ((u32)f2h(v.w) << 16);
        *(uint2*)&sX[r * 136 + k4] = make_uint2(p0, p1);
    }
    __syncthreads();

    const int wv   = tid >> 6;
    const int lane = tid & 63;
    const int m    = lane & 15;
    const int quad = lane >> 4;

    f16x8 bx[4];
    #pragma unroll
    for (int kc = 0; kc < 4; kc++)
        bx[kc] = *(const f16x8*)&sX[(wv * 16 + m) * 136 + kc * 32 + quad * 8];

    const int gn = row0 + wv * 16 + m;          // node (D col = lane&15)

    #pragma unroll
    for (int cb = 0; cb < 2; cb++) {
        const u16*   WT  = cb ? WTr : WTl;
        const float* bia = cb ? br  : bl;
        f32x4 acc[8] = {};
        #pragma unroll
        for (int kc = 0; kc < 4; kc++) {
            #pragma unroll
            for (int t = 0; t < 8; t++) {
                f16x8 aw = *(const f16x8*)&WT[(t * 16 + m) * 128 + kc * 32 + quad * 8];
                acc[t] = __builtin_amdgcn_mfma_f32_16x16x32_f16(aw, bx[kc], acc[t], 0, 0, 0);
            }
        }
        if (gn < N) {
            u16* dst = cb ? xr_p : xl_p;
            #pragma unroll
            for (int t = 0; t < 8; t++) {
                const int c0 = t * 16 + quad * 4;   // D row = quad*4+r
                float4 bv = *(const float4*)(bia + c0);
                u32 p0 = (u32)f2h(acc[t][0] + bv.x) | ((u32)f2h(acc[t][1] + bv.y) << 16);
                u32 p1 = (u32)f2h(acc[t][2] + bv.z) | ((u32)f2h(acc[t][3] + bv.w) << 16);
                *(uint2*)(dst + (size_t)gn * HD + c0) = make_uint2(p0, p1);
            }
        }
    }
}

// ---------------------------------------------------------------------------
// K3: edge softmax-aggregate + final linear + LayerNorm (measured-best
// config: LB(256,6), uint4 gathers, fp16 packed math, u16 bucket).
// ---------------------------------------------------------------------------
template<int D>
__device__ __forceinline__ void edge_block(
    int myidx, int j, int sgbase, const char* xbase,
    const h2* xr2, const h2* at2, h2 c02,
    h2* acc2, float& lden)
{
    uint4 q[D];
    #pragma unroll
    for (int b = 0; b < D; b++) {
        u32 off = (u32)__shfl(myidx, sgbase + j + 2 * b) << 8;
        q[b] = *(const uint4*)(xbase + off);
    }
    float sh[D];
    #pragma unroll
    for (int b = 0; b < D; b++) {
        h2 v0 = U2H(q[b].x) + xr2[0];
        h2 v1 = U2H(q[b].y) + xr2[1];
        h2 v2 = U2H(q[b].z) + xr2[2];
        h2 v3 = U2H(q[b].w) + xr2[3];
        v0 = U2H(pkmax(H2Ub(v0), H2Ub(v0 * c02)));
        v1 = U2H(pkmax(H2Ub(v1), H2Ub(v1 * c02)));
        v2 = U2H(pkmax(H2Ub(v2), H2Ub(v2 * c02)));
        v3 = U2H(pkmax(H2Ub(v3), H2Ub(v3 * c02)));
        float s = fdot2f(v0, at2[0], 0.f);
        s = fdot2f(v1, at2[1], s);
        s = fdot2f(v2, at2[2], s);
        s = fdot2f(v3, at2[3], s);
        sh[b] = s;
    }
    #pragma unroll
    for (int m = 4; m; m >>= 1) {
        #pragma unroll
        for (int b = 0; b < D; b++) sh[b] += __shfl_xor(sh[b], m);
    }
    #pragma unroll
    for (int b = 0; b < D; b++) {
        float p = exp2f(sh[b]);
        lden += p;
        _Float16 ph = (_Float16)p;
        h2 p2 = {ph, ph};
        acc2[0] += p2 * U2H(q[b].x);
        acc2[1] += p2 * U2H(q[b].y);
        acc2[2] += p2 * U2H(q[b].z);
        acc2[3] += p2 * U2H(q[b].w);
    }
}

__global__ __launch_bounds__(256, 6) void k_edge(
    const u16* __restrict__ xl_p, const u16* __restrict__ xr_p,
    const float* __restrict__ att, const float* __restrict__ bias,
    const uint4* __restrict__ Wfp, const float* __restrict__ bf,
    const float* __restrict__ gamma, const float* __restrict__ beta,
    const int* __restrict__ count, const u16* __restrict__ bucket,
    float* __restrict__ out, int N)
{
    __shared__ uint4 sWp[1024];         // 16 KB packed fp16 Wf
    __shared__ u32   sAggU[8 * 64];     // 2 KB

    const int tid = threadIdx.x;
    for (int idx = tid; idx < 1024; idx += 256) sWp[idx] = Wfp[idx];
    __syncthreads();

    const int l      = tid & 63;
    const int half   = tid >> 5;
    const int hl     = tid & 31;
    const int g16    = l & 15;
    const int ch0    = g16 * 8;
    const int sgsel  = (l >> 4) & 1;
    const int sgbase = (l & 32) + sgsel;
    const int n      = blockIdx.x * 8 + half;
    const bool active = (n < N);

    const h2 c02 = {(_Float16)0.2f, (_Float16)0.2f};
    h2 at2[4], xr2[4];
    {
        const float L2E = 1.44269504f;
        float4 a0 = *(const float4*)(att + ch0);
        float4 a1 = *(const float4*)(att + ch0 + 4);
        at2[0] = h2{(_Float16)(a0.x * L2E), (_Float16)(a0.y * L2E)};
        at2[1] = h2{(_Float16)(a0.z * L2E), (_Float16)(a0.w * L2E)};
        at2[2] = h2{(_Float16)(a1.x * L2E), (_Float16)(a1.y * L2E)};
        at2[3] = h2{(_Float16)(a1.z * L2E), (_Float16)(a1.w * L2E)};
        uint4 pr = make_uint4(0, 0, 0, 0);
        if (active) pr = *(const uint4*)(xr_p + (size_t)n * HD + ch0);
        xr2[0] = U2H(pr.x); xr2[1] = U2H(pr.y);
        xr2[2] = U2H(pr.z); xr2[3] = U2H(pr.w);
    }

    h2 acc2[4] = {};
    float lden = 0.f;

    int cnt_b = 0;
    if (active) {
        cnt_b = count[n];
        if (cnt_b < 0) cnt_b = 0;
        if (cnt_b > BCAP) cnt_b = BCAP;
    }
    const int cnt = active ? cnt_b + 1 : 0;   // + virtual self loop
    const u16* mybkt = bucket + (size_t)(active ? n : 0) * BCAP;

    const char* xbase = (const char*)xl_p + ch0 * 2;

    int done = 0;
    while (done < cnt) {
        int chunk = cnt - done; if (chunk > 32) chunk = 32;
        int myidx = 0;
        if (hl < chunk) {
            int gj = done + hl;
            myidx = (gj < cnt_b) ? (int)mybkt[gj] : n;
        }
        int j = 0;
        for (; j + 16 <= chunk; j += 16)
            edge_block<8>(myidx, j, sgbase, xbase, xr2, at2, c02, acc2, lden);
        if (j + 8 <= chunk) {
            edge_block<4>(myidx, j, sgbase, xbase, xr2, at2, c02, acc2, lden);
            j += 8;
        }
        if (j + 4 <= chunk) {
            edge_block<2>(myidx, j, sgbase, xbase, xr2, at2, c02, acc2, lden);
            j += 4;
        }
        for (; j < chunk; j += 2) {
            u32 off = (u32)__shfl(myidx, sgbase + j) << 8;
            uint4 q = *(const uint4*)(xbase + off);
            h2 v0 = U2H(q.x) + xr2[0];
            h2 v1 = U2H(q.y) + xr2[1];
            h2 v2 = U2H(q.z) + xr2[2];
            h2 v3 = U2H(q.w) + xr2[3];
            v0 = U2H(pkmax(H2Ub(v0), H2Ub(v0 * c02)));
            v1 = U2H(pkmax(H2Ub(v1), H2Ub(v1 * c02)));
            v2 = U2H(pkmax(H2Ub(v2), H2Ub(v2 * c02)));
            v3 = U2H(pkmax(H2Ub(v3), H2Ub(v3 * c02)));
            float s = fdot2f(v0, at2[0], 0.f);
            s = fdot2f(v1, at2[1], s);
            s = fdot2f(v2, at2[2], s);
            s = fdot2f(v3, at2[3], s);
            #pragma unroll
            for (int m = 4; m; m >>= 1) s += __shfl_xor(s, m);
            float p = (j + sgsel < chunk) ? exp2f(s) : 0.f;
            lden += p;
            _Float16 ph = (_Float16)p;
            h2 p2 = {ph, ph};
            acc2[0] += p2 * U2H(q.x);
            acc2[1] += p2 * U2H(q.y);
            acc2[2] += p2 * U2H(q.z);
            acc2[3] += p2 * U2H(q.w);
        }
        done += chunk;
    }

    #pragma unroll
    for (int i = 0; i < 4; i++) {
        u32 o = (u32)__shfl_xor((int)H2Ub(acc2[i]), 16);
        acc2[i] = acc2[i] + U2H(o);
    }
    lden += __shfl_xor(lden, 16);

    float rl = 1.f / fmaxf(lden, 1e-30f);
    if (!(l & 16)) {
        float4 b0 = *(const float4*)(bias + ch0);
        float4 b1 = *(const float4*)(bias + ch0 + 4);
        uint4 w;
        w.x = (u32)f2h((float)acc2[0][0] * rl + b0.x) |
              ((u32)f2h((float)acc2[0][1] * rl + b0.y) << 16);
        w.y = (u32)f2h((float)acc2[1][0] * rl + b0.z) |
              ((u32)f2h((float)acc2[1][1] * rl + b0.w) << 16);
        w.z = (u32)f2h((float)acc2[2][0] * rl + b1.x) |
              ((u32)f2h((float)acc2[2][1] * rl + b1.y) << 16);
        w.w = (u32)f2h((float)acc2[3][0] * rl + b1.z) |
              ((u32)f2h((float)acc2[3][1] * rl + b1.w) << 16);
        *(uint4*)&sAggU[half * 64 + g16 * 4] = w;
    }
    asm volatile("s_waitcnt lgkmcnt(0)" ::: "memory");   // same-wave DS visibility

    float h0 = bf[hl], h1 = bf[hl + 32];
    #pragma unroll 8
    for (int k4 = 0; k4 < 32; k4++) {
        uint4 wp = sWp[k4 * 32 + hl];
        uint2 ag = *(const uint2*)&sAggU[half * 64 + k4 * 2];
        h0 = fdot2f(U2H(ag.x), U2H(wp.x), h0);
        h0 = fdot2f(U2H(ag.y), U2H(wp.y), h0);
        h1 = fdot2f(U2H(ag.x), U2H(wp.z), h1);
        h1 = fdot2f(U2H(ag.y), U2H(wp.w), h1);
    }

    float s1r = h0 + h1, s2r = h0 * h0 + h1 * h1;
    #pragma unroll
    for (int m = 16; m; m >>= 1) { s1r += __shfl_xor(s1r, m); s2r += __shfl_xor(s2r, m); }
    float mu  = s1r * (1.f / 64.f);
    float var = s2r * (1.f / 64.f) - mu * mu;
    float rs  = rsqrtf(fmaxf(var, 0.f) + 1e-5f);
    if (active) {
        out[(size_t)n * DOUT + hl]      = (h0 - mu) * rs * gamma[hl]      + beta[hl];
        out[(size_t)n * DOUT + hl + 32] = (h1 - mu) * rs * gamma[hl + 32] + beta[hl + 32];
    }
}

// ---------------------------------------------------------------------------
extern "C" void kernel_launch(void* const* d_in, const int* in_sizes, int n_in,
                              void* d_out, int out_size, void* d_ws, size_t ws_size,
                              hipStream_t stream) {
    const float* X    = (const float*)d_in[0];
    const int*   E    = (const int*)d_in[1];
    const float* attr = (const float*)d_in[2];
    const float* Wl   = (const float*)d_in[3];
    const float* bl   = (const float*)d_in[4];
    const float* Wr   = (const float*)d_in[5];
    const float* br   = (const float*)d_in[6];
    const float* att  = (const float*)d_in[7];
    const float* bias = (const float*)d_in[8];
    const float* Wf   = (const float*)d_in[9];
    const float* bf   = (const float*)d_in[10];
    const float* gamma= (const float*)d_in[11];
    const float* beta = (const float*)d_in[12];
    float* out = (float*)d_out;

    const int N  = in_sizes[0] / DIN;
    const int NE = in_sizes[1] / 2;
    const int GB = (N + 63) / 64;

    char* ws = (char*)d_ws;
    int* count      = (int*)ws;               ws += (size_t)N * 4;
    u16* bucket     = (u16*)ws;               ws += (size_t)N * BCAP * 2;
    u16* xl_p       = (u16*)ws;               ws += (size_t)N * HD * 2;
    u16* xr_p       = (u16*)ws;               ws += (size_t)N * HD * 2;
    u16* WTl        = (u16*)ws;               ws += 128 * 128 * 2;
    u16* WTr        = (u16*)ws;               ws += 128 * 128 * 2;
    uint4* Wfp      = (uint4*)ws;             ws += 1024 * 16;
    int* q          = (int*)ws;               ws += 64;

    const int prep_items = N + 33800;
    k_prep<<<(prep_items + 255) / 256, 256, 0, stream>>>(
        Wl, Wr, Wf, WTl, WTr, Wfp, count, q, N);

    k_scatter_xq<<<2048, 256, 0, stream>>>(E, attr, count, bucket, q, out, N, NE);

    gemm1<<<GB, 256, 0, stream>>>(X, WTl, bl, WTr, br, xl_p, xr_p, N);

    k_edge<<<(N + 7) / 8, 256, 0, stream>>>(
        xl_p, xr_p, att, bias, Wfp, bf, gamma, beta, count, bucket, out, N);
}

// Round 16
// 225.313 us; speedup vs baseline: 1.8697x; 1.8697x over previous
//
#include <hip/hip_runtime.h>

typedef unsigned short u16;
typedef unsigned int   u32;

// RESOLVED (rounds 0-10): d_out is FLOAT32. Inputs f32. din=128, hd=128
// (H=2, dout=64), N=in_sizes[0]/128, NE=in_sizes[1]/2.
// Outputs flat f32: H_out [0,N*64) ; E [N*64,+2NE) ; attr [+NE).
// R17: fp16 (absmax .0156). R22: total-kernel_sum ~65us fixed -> launches
//      ~free; kernel time is the only lever.
// R23 (BEST 210): k_work = scatter+passthrough+gemm fused (82us) + k_edge
//      (58us). Scatter floor ~55-60us.
// R24-R27: four attacks on the scatter floor ALL failed (serial segmented
//      244; b%8 partition null 233; XCD-affine queues 421 — queue atomics
//      + 8x E rescan). WRITE 54->39.5MB with true affinity proves per-XCD
//      dirty-copy is real but SMALL. Verdict: scatter floor is atomic-issue
//      latency, not write amplification. Keep it hidden under k_work.
// R28: R23 verbatim + R24's single-X-staging gemm tile (stage X once per
//      64 rows, both heads via cb loop, W^T from global/L1). TT=GB; grid
//      2*GB -> each block still <=1 tile, no sX re-stage race.

#define DIN   128
#define DOUT  64
#define HD    128   // H * DOUT
#define BCAP  64    // bucket capacity per node

typedef __attribute__((ext_vector_type(8))) _Float16 f16x8;
typedef __attribute__((ext_vector_type(2))) _Float16 h2;
typedef __attribute__((ext_vector_type(4))) float    f32x4;

union H2U { u32 u; h2 h; };
__device__ __forceinline__ h2  U2H(u32 u) { H2U x; x.u = u; return x.h; }
__device__ __forceinline__ u32 H2Ub(h2 h) { H2U x; x.h = h; return x.u; }

__device__ __forceinline__ u16 f2h(float f) {
    _Float16 h = (_Float16)f;              // RNE
    u16 r; __builtin_memcpy(&r, &h, 2); return r;
}

// packed fp16 max via ISA (v_pk_max_f16 is VOP3P, present on gfx950)
__device__ __forceinline__ u32 pkmax(u32 a, u32 b) {
    u32 d;
    asm("v_pk_max_f16 %0, %1, %2" : "=v"(d) : "v"(a), "v"(b));
    return d;
}

__device__ __forceinline__ float fdot2f(h2 a, h2 b, float c) {
#if __has_builtin(__builtin_amdgcn_fdot2)
    return __builtin_amdgcn_fdot2(a, b, c, false);
#else
    return c + (float)a[0] * (float)b[0] + (float)a[1] * (float)b[1];
#endif
}

// ---------------------------------------------------------------------------
// phase-0 item: zero count + WT transpose->fp16 + Wfp pack
// ---------------------------------------------------------------------------
__device__ __forceinline__ void dev_prep_item(
    int i, const float* __restrict__ Wl, const float* __restrict__ Wr,
    const float* __restrict__ Wf, u16* __restrict__ WTl, u16* __restrict__ WTr,
    uint4* __restrict__ Wfp, int* __restrict__ count, int N)
{
    if (i < N) { count[i] = 0; return; }
    int j = i - N;
    if (j < 16384) {
        int k = j >> 7, c = j & 127;
        WTl[c * 128 + k] = f2h(Wl[j]);
    } else if (j < 32768) {
        int t = j - 16384;
        int k = t >> 7, c = t & 127;
        WTr[c * 128 + k] = f2h(Wr[t]);
    } else if (j < 33792) {
        int t = j - 32768;
        int k4 = t >> 5, c = t & 31;
        const float* wrow = Wf + (size_t)(4 * k4) * DOUT;
        u32 a0 = (u32)f2h(wrow[c])              | ((u32)f2h(wrow[DOUT + c]) << 16);
        u32 a1 = (u32)f2h(wrow[2 * DOUT + c])   | ((u32)f2h(wrow[3 * DOUT + c]) << 16);
        u32 a2 = (u32)f2h(wrow[c + 32])         | ((u32)f2h(wrow[DOUT + c + 32]) << 16);
        u32 a3 = (u32)f2h(wrow[2 * DOUT + c + 32]) | ((u32)f2h(wrow[3 * DOUT + c + 32]) << 16);
        Wfp[t] = make_uint4(a0, a1, a2, a3);
    }
}

__global__ void k_prep(const float* __restrict__ Wl, const float* __restrict__ Wr,
                       const float* __restrict__ Wf, u16* __restrict__ WTl,
                       u16* __restrict__ WTr, uint4* __restrict__ Wfp,
                       int* __restrict__ count, int N)
{
    int i = blockIdx.x * 256 + threadIdx.x;
    if (i < N + 33792) dev_prep_item(i, Wl, Wr, Wf, WTl, WTr, Wfp, count, N);
}

// ---------------------------------------------------------------------------
// K1: k_work = bucket scatter + E/attr passthrough + MFMA GEMM.
// Grid = 2*GB blocks; tiles = GB (one per 64 rows, BOTH heads inside).
// Alternating roles by bid parity: half gemm-first, half scatter-first ->
// heterogeneous co-residency (atomic latency hides under MFMA).
// GEMM: X staged ONCE -> fp16 LDS (17.4KB only); W^T from GLOBAL (32KB,
// L1-hot); fragments in regs across cb loop. D col=node,row=c -> uint2.
// ---------------------------------------------------------------------------
__device__ __forceinline__ void dev_scatter_edge(
    int e, const int* __restrict__ E, int* __restrict__ count,
    u16* __restrict__ bucket, int N, int NE)
{
    int src = E[e];
    int dst = E[NE + e];
    if ((u32)dst >= (u32)N) dst = 0;
    if ((u32)src >= (u32)N) src = 0;
    int rank = atomicAdd(&count[dst], 1);
    if (rank < BCAP) bucket[(size_t)dst * BCAP + rank] = (u16)src;
}

__device__ __forceinline__ void dev_gemm_tile_both(
    int bt, int tid, u16* sX,
    const float* __restrict__ X,
    const u16* __restrict__ WTl, const float* __restrict__ bl,
    const u16* __restrict__ WTr, const float* __restrict__ br,
    u16* __restrict__ xl_p, u16* __restrict__ xr_p, int N)
{
    const int row0 = bt * 64;

    for (int idx = tid; idx < 64 * 32; idx += 256) {
        int r  = idx >> 5;
        int k4 = (idx & 31) << 2;
        int gr = row0 + r;
        float4 v = make_float4(0.f, 0.f, 0.f, 0.f);
        if (gr < N) v = *(const float4*)(X + (size_t)gr * DIN + k4);
        u32 p0 = (u32)f2h(v.x) | ((u32)f2h(v.y) << 16);
        u32 p1 = (u32)f2h(v.z) | ((u32)f2h(v.w) << 16);
        *(uint2*)&sX[r * 136 + k4] = make_uint2(p0, p1);
    }
    __syncthreads();

    const int wv   = tid >> 6;
    const int lane = tid & 63;
    const int m    = lane & 15;
    const int quad = lane >> 4;

    f16x8 bx[4];
    #pragma unroll
    for (int kc = 0; kc < 4; kc++)
        bx[kc] = *(const f16x8*)&sX[(wv * 16 + m) * 136 + kc * 32 + quad * 8];

    const int gn = row0 + wv * 16 + m;          // node (D col = lane&15)

    #pragma unroll
    for (int cb = 0; cb < 2; cb++) {
        const u16*   WT  = cb ? WTr : WTl;
        const float* bia = cb ? br  : bl;
        f32x4 acc[8] = {};
        #pragma unroll
        for (int kc = 0; kc < 4; kc++) {
            #pragma unroll
            for (int t = 0; t < 8; t++) {
                f16x8 aw = *(const f16x8*)&WT[(t * 16 + m) * 128 + kc * 32 + quad * 8];
                acc[t] = __builtin_amdgcn_mfma_f32_16x16x32_f16(aw, bx[kc], acc[t], 0, 0, 0);
            }
        }
        if (gn < N) {
            u16* dst = cb ? xr_p : xl_p;
            #pragma unroll
            for (int t = 0; t < 8; t++) {
                const int c0 = t * 16 + quad * 4;   // D row = quad*4+r
                float4 bv = *(const float4*)(bia + c0);
                u32 p0 = (u32)f2h(acc[t][0] + bv.x) | ((u32)f2h(acc[t][1] + bv.y) << 16);
                u32 p1 = (u32)f2h(acc[t][2] + bv.z) | ((u32)f2h(acc[t][3] + bv.w) << 16);
                *(uint2*)(dst + (size_t)gn * HD + c0) = make_uint2(p0, p1);
            }
        }
    }
}

__global__ __launch_bounds__(256) void k_work(
    const float* __restrict__ X, const int* __restrict__ E,
    const float* __restrict__ attr,
    const u16* __restrict__ WTl, const float* __restrict__ bl,
    const u16* __restrict__ WTr, const float* __restrict__ br,
    int* __restrict__ count, u16* __restrict__ bucket,
    u16* __restrict__ xl_p, u16* __restrict__ xr_p,
    float* __restrict__ out, int N, int NE, int GB)
{
    __shared__ u16 sX[64 * 136];    // 17408 B — only LDS in this kernel
    const int tid  = threadIdx.x;
    const int bid  = blockIdx.x;
    const int nB   = gridDim.x;
    const int gsz  = nB * 256;
    const int gtid = bid * 256 + tid;
    const int TT   = GB;            // one tile per 64 rows (both heads)

    if (bid & 1) {
        for (int bt = bid; bt < TT; bt += nB)
            dev_gemm_tile_both(bt, tid, sX, X, WTl, bl, WTr, br, xl_p, xr_p, N);
        for (int e = gtid; e < NE; e += gsz)
            dev_scatter_edge(e, E, count, bucket, N, NE);
    } else {
        for (int e = gtid; e < NE; e += gsz)
            dev_scatter_edge(e, E, count, bucket, N, NE);
        for (int bt = bid; bt < TT; bt += nB)
            dev_gemm_tile_both(bt, tid, sX, X, WTl, bl, WTr, br, xl_p, xr_p, N);
    }
    const size_t base = (size_t)N * DOUT;
    for (int p = gtid; p < 3 * NE; p += gsz) {
        if (p < 2 * NE) out[base + p] = (float)E[p];
        else            out[base + p] = attr[p - 2 * NE];
    }
}

// ---------------------------------------------------------------------------
// K2: edge softmax-aggregate + final linear + LayerNorm (measured-best
// config: LB(256,6), uint4 gathers, fp16 packed math, u16 bucket).
// ---------------------------------------------------------------------------
template<int D>
__device__ __forceinline__ void edge_block(
    int myidx, int j, int sgbase, const char* xbase,
    const h2* xr2, const h2* at2, h2 c02,
    h2* acc2, float& lden)
{
    uint4 q[D];
    #pragma unroll
    for (int b = 0; b < D; b++) {
        u32 off = (u32)__shfl(myidx, sgbase + j + 2 * b) << 8;
        q[b] = *(const uint4*)(xbase + off);
    }
    float sh[D];
    #pragma unroll
    for (int b = 0; b < D; b++) {
        h2 v0 = U2H(q[b].x) + xr2[0];
        h2 v1 = U2H(q[b].y) + xr2[1];
        h2 v2 = U2H(q[b].z) + xr2[2];
        h2 v3 = U2H(q[b].w) + xr2[3];
        v0 = U2H(pkmax(H2Ub(v0), H2Ub(v0 * c02)));
        v1 = U2H(pkmax(H2Ub(v1), H2Ub(v1 * c02)));
        v2 = U2H(pkmax(H2Ub(v2), H2Ub(v2 * c02)));
        v3 = U2H(pkmax(H2Ub(v3), H2Ub(v3 * c02)));
        float s = fdot2f(v0, at2[0], 0.f);
        s = fdot2f(v1, at2[1], s);
        s = fdot2f(v2, at2[2], s);
        s = fdot2f(v3, at2[3], s);
        sh[b] = s;
    }
    #pragma unroll
    for (int m = 4; m; m >>= 1) {
        #pragma unroll
        for (int b = 0; b < D; b++) sh[b] += __shfl_xor(sh[b], m);
    }
    #pragma unroll
    for (int b = 0; b < D; b++) {
        float p = exp2f(sh[b]);
        lden += p;
        _Float16 ph = (_Float16)p;
        h2 p2 = {ph, ph};
        acc2[0] += p2 * U2H(q[b].x);
        acc2[1] += p2 * U2H(q[b].y);
        acc2[2] += p2 * U2H(q[b].z);
        acc2[3] += p2 * U2H(q[b].w);
    }
}

__global__ __launch_bounds__(256, 6) void k_edge(
    const u16* __restrict__ xl_p, const u16* __restrict__ xr_p,
    const float* __restrict__ att, const float* __restrict__ bias,
    const uint4* __restrict__ Wfp, const float* __restrict__ bf,
    const float* __restrict__ gamma, const float* __restrict__ beta,
    const int* __restrict__ count, const u16* __restrict__ bucket,
    float* __restrict__ out, int N)
{
    __shared__ uint4 sWp[1024];         // 16 KB packed fp16 Wf
    __shared__ u32   sAggU[8 * 64];     // 2 KB

    const int tid = threadIdx.x;
    for (int idx = tid; idx < 1024; idx += 256) sWp[idx] = Wfp[idx];
    __syncthreads();

    const int l      = tid & 63;
    const int half   = tid >> 5;
    const int hl     = tid & 31;
    const int g16    = l & 15;
    const int ch0    = g16 * 8;
    const int sgsel  = (l >> 4) & 1;
    const int sgbase = (l & 32) + sgsel;
    const int n      = blockIdx.x * 8 + half;
    const bool active = (n < N);

    const h2 c02 = {(_Float16)0.2f, (_Float16)0.2f};
    h2 at2[4], xr2[4];
    {
        const float L2E = 1.44269504f;
        float4 a0 = *(const float4*)(att + ch0);
        float4 a1 = *(const float4*)(att + ch0 + 4);
        at2[0] = h2{(_Float16)(a0.x * L2E), (_Float16)(a0.y * L2E)};
        at2[1] = h2{(_Float16)(a0.z * L2E), (_Float16)(a0.w * L2E)};
        at2[2] = h2{(_Float16)(a1.x * L2E), (_Float16)(a1.y * L2E)};
        at2[3] = h2{(_Float16)(a1.z * L2E), (_Float16)(a1.w * L2E)};
        uint4 pr = make_uint4(0, 0, 0, 0);
        if (active) pr = *(const uint4*)(xr_p + (size_t)n * HD + ch0);
        xr2[0] = U2H(pr.x); xr2[1] = U2H(pr.y);
        xr2[2] = U2H(pr.z); xr2[3] = U2H(pr.w);
    }

    h2 acc2[4] = {};
    float lden = 0.f;

    int cnt_b = 0;
    if (active) {
        cnt_b = count[n];
        if (cnt_b < 0) cnt_b = 0;
        if (cnt_b > BCAP) cnt_b = BCAP;
    }
    const int cnt = active ? cnt_b + 1 : 0;   // + virtual self loop
    const u16* mybkt = bucket + (size_t)(active ? n : 0) * BCAP;

    const char* xbase = (const char*)xl_p + ch0 * 2;

    int done = 0;
    while (done < cnt) {
        int chunk = cnt - done; if (chunk > 32) chunk = 32;
        int myidx = 0;
        if (hl < chunk) {
            int gj = done + hl;
            myidx = (gj < cnt_b) ? (int)mybkt[gj] : n;
        }
        int j = 0;
        for (; j + 16 <= chunk; j += 16)
            edge_block<8>(myidx, j, sgbase, xbase, xr2, at2, c02, acc2, lden);
        if (j + 8 <= chunk) {
            edge_block<4>(myidx, j, sgbase, xbase, xr2, at2, c02, acc2, lden);
            j += 8;
        }
        if (j + 4 <= chunk) {
            edge_block<2>(myidx, j, sgbase, xbase, xr2, at2, c02, acc2, lden);
            j += 4;
        }
        for (; j < chunk; j += 2) {
            u32 off = (u32)__shfl(myidx, sgbase + j) << 8;
            uint4 q = *(const uint4*)(xbase + off);
            h2 v0 = U2H(q.x) + xr2[0];
            h2 v1 = U2H(q.y) + xr2[1];
            h2 v2 = U2H(q.z) + xr2[2];
            h2 v3 = U2H(q.w) + xr2[3];
            v0 = U2H(pkmax(H2Ub(v0), H2Ub(v0 * c02)));
            v1 = U2H(pkmax(H2Ub(v1), H2Ub(v1 * c02)));
            v2 = U2H(pkmax(H2Ub(v2), H2Ub(v2 * c02)));
            v3 = U2H(pkmax(H2Ub(v3), H2Ub(v3 * c02)));
            float s = fdot2f(v0, at2[0], 0.f);
            s = fdot2f(v1, at2[1], s);
            s = fdot2f(v2, at2[2], s);
            s = fdot2f(v3, at2[3], s);
            #pragma unroll
            for (int m = 4; m; m >>= 1) s += __shfl_xor(s, m);
            float p = (j + sgsel < chunk) ? exp2f(s) : 0.f;
            lden += p;
            _Float16 ph = (_Float16)p;
            h2 p2 = {ph, ph};
            acc2[0] += p2 * U2H(q.x);
            acc2[1] += p2 * U2H(q.y);
            acc2[2] += p2 * U2H(q.z);
            acc2[3] += p2 * U2H(q.w);
        }
        done += chunk;
    }

    #pragma unroll
    for (int i = 0; i < 4; i++) {
        u32 o = (u32)__shfl_xor((int)H2Ub(acc2[i]), 16);
        acc2[i] = acc2[i] + U2H(o);
    }
    lden += __shfl_xor(lden, 16);

    float rl = 1.f / fmaxf(lden, 1e-30f);
    if (!(l & 16)) {
        float4 b0 = *(const float4*)(bias + ch0);
        float4 b1 = *(const float4*)(bias + ch0 + 4);
        uint4 w;
        w.x = (u32)f2h((float)acc2[0][0] * rl + b0.x) |
              ((u32)f2h((float)acc2[0][1] * rl + b0.y) << 16);
        w.y = (u32)f2h((float)acc2[1][0] * rl + b0.z) |
              ((u32)f2h((float)acc2[1][1] * rl + b0.w) << 16);
        w.z = (u32)f2h((float)acc2[2][0] * rl + b1.x) |
              ((u32)f2h((float)acc2[2][1] * rl + b1.y) << 16);
        w.w = (u32)f2h((float)acc2[3][0] * rl + b1.z) |
              ((u32)f2h((float)acc2[3][1] * rl + b1.w) << 16);
        *(uint4*)&sAggU[half * 64 + g16 * 4] = w;
    }
    asm volatile("s_waitcnt lgkmcnt(0)" ::: "memory");   // same-wave DS visibility

    float h0 = bf[hl], h1 = bf[hl + 32];
    #pragma unroll 8
    for (int k4 = 0; k4 < 32; k4++) {
        uint4 wp = sWp[k4 * 32 + hl];
        uint2 ag = *(const uint2*)&sAggU[half * 64 + k4 * 2];
        h0 = fdot2f(U2H(ag.x), U2H(wp.x), h0);
        h0 = fdot2f(U2H(ag.y), U2H(wp.y), h0);
        h1 = fdot2f(U2H(ag.x), U2H(wp.z), h1);
        h1 = fdot2f(U2H(ag.y), U2H(wp.w), h1);
    }

    float s1r = h0 + h1, s2r = h0 * h0 + h1 * h1;
    #pragma unroll
    for (int m = 16; m; m >>= 1) { s1r += __shfl_xor(s1r, m); s2r += __shfl_xor(s2r, m); }
    float mu  = s1r * (1.f / 64.f);
    float var = s2r * (1.f / 64.f) - mu * mu;
    float rs  = rsqrtf(fmaxf(var, 0.f) + 1e-5f);
    if (active) {
        out[(size_t)n * DOUT + hl]      = (h0 - mu) * rs * gamma[hl]      + beta[hl];
        out[(size_t)n * DOUT + hl + 32] = (h1 - mu) * rs * gamma[hl + 32] + beta[hl + 32];
    }
}

// ---------------------------------------------------------------------------
extern "C" void kernel_launch(void* const* d_in, const int* in_sizes, int n_in,
                              void* d_out, int out_size, void* d_ws, size_t ws_size,
                              hipStream_t stream) {
    const float* X    = (const float*)d_in[0];
    const int*   E    = (const int*)d_in[1];
    const float* attr = (const float*)d_in[2];
    const float* Wl   = (const float*)d_in[3];
    const float* bl   = (const float*)d_in[4];
    const float* Wr   = (const float*)d_in[5];
    const float* br   = (const float*)d_in[6];
    const float* att  = (const float*)d_in[7];
    const float* bias = (const float*)d_in[8];
    const float* Wf   = (const float*)d_in[9];
    const float* bf   = (const float*)d_in[10];
    const float* gamma= (const float*)d_in[11];
    const float* beta = (const float*)d_in[12];
    float* out = (float*)d_out;

    const int N  = in_sizes[0] / DIN;
    const int NE = in_sizes[1] / 2;
    const int GB = (N + 63) / 64;

    char* ws = (char*)d_ws;
    int* count      = (int*)ws;               ws += (size_t)N * 4;
    u16* bucket     = (u16*)ws;               ws += (size_t)N * BCAP * 2;
    u16* xl_p       = (u16*)ws;               ws += (size_t)N * HD * 2;
    u16* xr_p       = (u16*)ws;               ws += (size_t)N * HD * 2;
    u16* WTl        = (u16*)ws;               ws += 128 * 128 * 2;
    u16* WTr        = (u16*)ws;               ws += 128 * 128 * 2;
    uint4* Wfp      = (uint4*)ws;             ws += 1024 * 16;

    k_prep<<<(N + 33792 + 255) / 256, 256, 0, stream>>>(
        Wl, Wr, Wf, WTl, WTr, Wfp, count, N);

    k_work<<<2 * GB, 256, 0, stream>>>(
        X, E, attr, WTl, bl, WTr, br, count, bucket, xl_p, xr_p, out, N, NE, GB);

    k_edge<<<(N + 7) / 8, 256, 0, stream>>>(
        xl_p, xr_p, att, bias, Wfp, bf, gamma, beta, count, bucket, out, N);
}

// Round 17
// 212.329 us; speedup vs baseline: 1.9841x; 1.0611x over previous
//
#include <hip/hip_runtime.h>

typedef unsigned short u16;
typedef unsigned int   u32;

// RESOLVED (rounds 0-10): d_out is FLOAT32. Inputs f32. din=128, hd=128
// (H=2, dout=64), N=in_sizes[0]/128, NE=in_sizes[1]/2.
// Outputs flat f32: H_out [0,N*64) ; E [N*64,+2NE) ; attr [+NE).
// R17: fp16 (absmax .0156). R22: total-kernel_sum ~65us fixed -> launches
//      ~free; kernel time is the only lever.
// R23 (BEST 210): k_work = scatter+passthrough+gemm fused (82us, VGPR 60,
//      occ 30%) + k_edge (58us). Scatter floor ~55-60us.
// R24-R27: four attacks on the scatter floor ALL failed. Verdict: scatter
//      floor is atomic-issue latency; keep it hidden under k_work.
// R28: both-heads gemm tile REGRESSED (225): VGPR 60->176 (bx[4] + 2x acc
//      interleaved) -> occ 10% -> scatter TLP strangled. FETCH -13MB was
//      worth ~2us; occupancy loss cost ~15us. OCCUPANCY DOMINATES TRAFFIC
//      in this fused kernel (3rd confirmation: R21 LDS, R22 coop, R28 VGPR).
// R29: R23 k_work restored verbatim (per-head tiles, cb=bt&1, TT=2*GB,
//      60 VGPR). Everything else measured-best. Confirm the 210 plateau.

#define DIN   128
#define DOUT  64
#define HD    128   // H * DOUT
#define BCAP  64    // bucket capacity per node

typedef __attribute__((ext_vector_type(8))) _Float16 f16x8;
typedef __attribute__((ext_vector_type(2))) _Float16 h2;
typedef __attribute__((ext_vector_type(4))) float    f32x4;

union H2U { u32 u; h2 h; };
__device__ __forceinline__ h2  U2H(u32 u) { H2U x; x.u = u; return x.h; }
__device__ __forceinline__ u32 H2Ub(h2 h) { H2U x; x.h = h; return x.u; }

__device__ __forceinline__ u16 f2h(float f) {
    _Float16 h = (_Float16)f;              // RNE
    u16 r; __builtin_memcpy(&r, &h, 2); return r;
}

// packed fp16 max via ISA (v_pk_max_f16 is VOP3P, present on gfx950)
__device__ __forceinline__ u32 pkmax(u32 a, u32 b) {
    u32 d;
    asm("v_pk_max_f16 %0, %1, %2" : "=v"(d) : "v"(a), "v"(b));
    return d;
}

__device__ __forceinline__ float fdot2f(h2 a, h2 b, float c) {
#if __has_builtin(__builtin_amdgcn_fdot2)
    return __builtin_amdgcn_fdot2(a, b, c, false);
#else
    return c + (float)a[0] * (float)b[0] + (float)a[1] * (float)b[1];
#endif
}

// ---------------------------------------------------------------------------
// phase-0 item: zero count + WT transpose->fp16 + Wfp pack
// ---------------------------------------------------------------------------
__device__ __forceinline__ void dev_prep_item(
    int i, const float* __restrict__ Wl, const float* __restrict__ Wr,
    const float* __restrict__ Wf, u16* __restrict__ WTl, u16* __restrict__ WTr,
    uint4* __restrict__ Wfp, int* __restrict__ count, int N)
{
    if (i < N) { count[i] = 0; return; }
    int j = i - N;
    if (j < 16384) {
        int k = j >> 7, c = j & 127;
        WTl[c * 128 + k] = f2h(Wl[j]);
    } else if (j < 32768) {
        int t = j - 16384;
        int k = t >> 7, c = t & 127;
        WTr[c * 128 + k] = f2h(Wr[t]);
    } else if (j < 33792) {
        int t = j - 32768;
        int k4 = t >> 5, c = t & 31;
        const float* wrow = Wf + (size_t)(4 * k4) * DOUT;
        u32 a0 = (u32)f2h(wrow[c])              | ((u32)f2h(wrow[DOUT + c]) << 16);
        u32 a1 = (u32)f2h(wrow[2 * DOUT + c])   | ((u32)f2h(wrow[3 * DOUT + c]) << 16);
        u32 a2 = (u32)f2h(wrow[c + 32])         | ((u32)f2h(wrow[DOUT + c + 32]) << 16);
        u32 a3 = (u32)f2h(wrow[2 * DOUT + c + 32]) | ((u32)f2h(wrow[3 * DOUT + c + 32]) << 16);
        Wfp[t] = make_uint4(a0, a1, a2, a3);
    }
}

__global__ void k_prep(const float* __restrict__ Wl, const float* __restrict__ Wr,
                       const float* __restrict__ Wf, u16* __restrict__ WTl,
                       u16* __restrict__ WTr, uint4* __restrict__ Wfp,
                       int* __restrict__ count, int N)
{
    int i = blockIdx.x * 256 + threadIdx.x;
    if (i < N + 33792) dev_prep_item(i, Wl, Wr, Wf, WTl, WTr, Wfp, count, N);
}

// ---------------------------------------------------------------------------
// K1: k_work = bucket scatter + E/attr passthrough + MFMA GEMM.
// Grid = 2*GB blocks; cb = bt&1, tile row0 = (bt>>1)*64 (per-head tiles:
// 60 VGPR -> occ ~30%, the measured optimum; both-heads variant hit 176
// VGPR / occ 10% and regressed). Alternating roles by bid parity ->
// heterogeneous co-residency (atomic latency hides under MFMA).
// GEMM: A = W^T from GLOBAL (32KB, L1-hot), B = X via LDS (17.4KB only).
// D col=node, row=c -> packed uint2 stores.
// ---------------------------------------------------------------------------
__device__ __forceinline__ void dev_scatter_edge(
    int e, const int* __restrict__ E, int* __restrict__ count,
    u16* __restrict__ bucket, int N, int NE)
{
    int src = E[e];
    int dst = E[NE + e];
    if ((u32)dst >= (u32)N) dst = 0;
    if ((u32)src >= (u32)N) src = 0;
    int rank = atomicAdd(&count[dst], 1);
    if (rank < BCAP) bucket[(size_t)dst * BCAP + rank] = (u16)src;
}

__device__ __forceinline__ void dev_gemm_tile(
    int bt, int tid, u16* sX,
    const float* __restrict__ X,
    const u16* __restrict__ WTl, const float* __restrict__ bl,
    const u16* __restrict__ WTr, const float* __restrict__ br,
    u16* __restrict__ xl_p, u16* __restrict__ xr_p, int N)
{
    const int cb   = bt & 1;
    const int row0 = (bt >> 1) * 64;
    const u16*   WT  = cb ? WTr : WTl;
    const float* bia = cb ? br : bl;

    for (int idx = tid; idx < 64 * 32; idx += 256) {
        int r  = idx >> 5;
        int k4 = (idx & 31) << 2;
        int gr = row0 + r;
        float4 v = make_float4(0.f, 0.f, 0.f, 0.f);
        if (gr < N) v = *(const float4*)(X + (size_t)gr * DIN + k4);
        u32 p0 = (u32)f2h(v.x) | ((u32)f2h(v.y) << 16);
        u32 p1 = (u32)f2h(v.z) | ((u32)f2h(v.w) << 16);
        *(uint2*)&sX[r * 136 + k4] = make_uint2(p0, p1);
    }
    __syncthreads();

    const int wv   = tid >> 6;
    const int lane = tid & 63;
    const int m    = lane & 15;
    const int quad = lane >> 4;

    f32x4 acc[8] = {};
    #pragma unroll
    for (int kc = 0; kc < 4; kc++) {
        f16x8 bx = *(const f16x8*)&sX[(wv * 16 + m) * 136 + kc * 32 + quad * 8];
        #pragma unroll
        for (int t = 0; t < 8; t++) {
            f16x8 aw = *(const f16x8*)&WT[(t * 16 + m) * 128 + kc * 32 + quad * 8];
            acc[t] = __builtin_amdgcn_mfma_f32_16x16x32_f16(aw, bx, acc[t], 0, 0, 0);
        }
    }

    const int gn = row0 + wv * 16 + m;          // node (D col = lane&15)
    if (gn < N) {
        u16* dst = cb ? xr_p : xl_p;
        #pragma unroll
        for (int t = 0; t < 8; t++) {
            const int c0 = t * 16 + quad * 4;   // D row = quad*4+r
            float4 bv = *(const float4*)(bia + c0);
            u32 p0 = (u32)f2h(acc[t][0] + bv.x) | ((u32)f2h(acc[t][1] + bv.y) << 16);
            u32 p1 = (u32)f2h(acc[t][2] + bv.z) | ((u32)f2h(acc[t][3] + bv.w) << 16);
            *(uint2*)(dst + (size_t)gn * HD + c0) = make_uint2(p0, p1);
        }
    }
}

__global__ __launch_bounds__(256) void k_work(
    const float* __restrict__ X, const int* __restrict__ E,
    const float* __restrict__ attr,
    const u16* __restrict__ WTl, const float* __restrict__ bl,
    const u16* __restrict__ WTr, const float* __restrict__ br,
    int* __restrict__ count, u16* __restrict__ bucket,
    u16* __restrict__ xl_p, u16* __restrict__ xr_p,
    float* __restrict__ out, int N, int NE, int GB)
{
    __shared__ u16 sX[64 * 136];    // 17408 B — only LDS in this kernel
    const int tid  = threadIdx.x;
    const int bid  = blockIdx.x;
    const int nB   = gridDim.x;
    const int gsz  = nB * 256;
    const int gtid = bid * 256 + tid;
    const int TT   = 2 * GB;

    if (bid & 1) {
        for (int bt = bid; bt < TT; bt += nB)
            dev_gemm_tile(bt, tid, sX, X, WTl, bl, WTr, br, xl_p, xr_p, N);
        for (int e = gtid; e < NE; e += gsz)
            dev_scatter_edge(e, E, count, bucket, N, NE);
    } else {
        for (int e = gtid; e < NE; e += gsz)
            dev_scatter_edge(e, E, count, bucket, N, NE);
        for (int bt = bid; bt < TT; bt += nB)
            dev_gemm_tile(bt, tid, sX, X, WTl, bl, WTr, br, xl_p, xr_p, N);
    }
    const size_t base = (size_t)N * DOUT;
    for (int p = gtid; p < 3 * NE; p += gsz) {
        if (p < 2 * NE) out[base + p] = (float)E[p];
        else            out[base + p] = attr[p - 2 * NE];
    }
}

// ---------------------------------------------------------------------------
// K2: edge softmax-aggregate + final linear + LayerNorm (measured-best
// config: LB(256,6), uint4 gathers, fp16 packed math, u16 bucket).
// ---------------------------------------------------------------------------
template<int D>
__device__ __forceinline__ void edge_block(
    int myidx, int j, int sgbase, const char* xbase,
    const h2* xr2, const h2* at2, h2 c02,
    h2* acc2, float& lden)
{
    uint4 q[D];
    #pragma unroll
    for (int b = 0; b < D; b++) {
        u32 off = (u32)__shfl(myidx, sgbase + j + 2 * b) << 8;
        q[b] = *(const uint4*)(xbase + off);
    }
    float sh[D];
    #pragma unroll
    for (int b = 0; b < D; b++) {
        h2 v0 = U2H(q[b].x) + xr2[0];
        h2 v1 = U2H(q[b].y) + xr2[1];
        h2 v2 = U2H(q[b].z) + xr2[2];
        h2 v3 = U2H(q[b].w) + xr2[3];
        v0 = U2H(pkmax(H2Ub(v0), H2Ub(v0 * c02)));
        v1 = U2H(pkmax(H2Ub(v1), H2Ub(v1 * c02)));
        v2 = U2H(pkmax(H2Ub(v2), H2Ub(v2 * c02)));
        v3 = U2H(pkmax(H2Ub(v3), H2Ub(v3 * c02)));
        float s = fdot2f(v0, at2[0], 0.f);
        s = fdot2f(v1, at2[1], s);
        s = fdot2f(v2, at2[2], s);
        s = fdot2f(v3, at2[3], s);
        sh[b] = s;
    }
    #pragma unroll
    for (int m = 4; m; m >>= 1) {
        #pragma unroll
        for (int b = 0; b < D; b++) sh[b] += __shfl_xor(sh[b], m);
    }
    #pragma unroll
    for (int b = 0; b < D; b++) {
        float p = exp2f(sh[b]);
        lden += p;
        _Float16 ph = (_Float16)p;
        h2 p2 = {ph, ph};
        acc2[0] += p2 * U2H(q[b].x);
        acc2[1] += p2 * U2H(q[b].y);
        acc2[2] += p2 * U2H(q[b].z);
        acc2[3] += p2 * U2H(q[b].w);
    }
}

__global__ __launch_bounds__(256, 6) void k_edge(
    const u16* __restrict__ xl_p, const u16* __restrict__ xr_p,
    const float* __restrict__ att, const float* __restrict__ bias,
    const uint4* __restrict__ Wfp, const float* __restrict__ bf,
    const float* __restrict__ gamma, const float* __restrict__ beta,
    const int* __restrict__ count, const u16* __restrict__ bucket,
    float* __restrict__ out, int N)
{
    __shared__ uint4 sWp[1024];         // 16 KB packed fp16 Wf
    __shared__ u32   sAggU[8 * 64];     // 2 KB

    const int tid = threadIdx.x;
    for (int idx = tid; idx < 1024; idx += 256) sWp[idx] = Wfp[idx];
    __syncthreads();

    const int l      = tid & 63;
    const int half   = tid >> 5;
    const int hl     = tid & 31;
    const int g16    = l & 15;
    const int ch0    = g16 * 8;
    const int sgsel  = (l >> 4) & 1;
    const int sgbase = (l & 32) + sgsel;
    const int n      = blockIdx.x * 8 + half;
    const bool active = (n < N);

    const h2 c02 = {(_Float16)0.2f, (_Float16)0.2f};
    h2 at2[4], xr2[4];
    {
        const float L2E = 1.44269504f;
        float4 a0 = *(const float4*)(att + ch0);
        float4 a1 = *(const float4*)(att + ch0 + 4);
        at2[0] = h2{(_Float16)(a0.x * L2E), (_Float16)(a0.y * L2E)};
        at2[1] = h2{(_Float16)(a0.z * L2E), (_Float16)(a0.w * L2E)};
        at2[2] = h2{(_Float16)(a1.x * L2E), (_Float16)(a1.y * L2E)};
        at2[3] = h2{(_Float16)(a1.z * L2E), (_Float16)(a1.w * L2E)};
        uint4 pr = make_uint4(0, 0, 0, 0);
        if (active) pr = *(const uint4*)(xr_p + (size_t)n * HD + ch0);
        xr2[0] = U2H(pr.x); xr2[1] = U2H(pr.y);
        xr2[2] = U2H(pr.z); xr2[3] = U2H(pr.w);
    }

    h2 acc2[4] = {};
    float lden = 0.f;

    int cnt_b = 0;
    if (active) {
        cnt_b = count[n];
        if (cnt_b < 0) cnt_b = 0;
        if (cnt_b > BCAP) cnt_b = BCAP;
    }
    const int cnt = active ? cnt_b + 1 : 0;   // + virtual self loop
    const u16* mybkt = bucket + (size_t)(active ? n : 0) * BCAP;

    const char* xbase = (const char*)xl_p + ch0 * 2;

    int done = 0;
    while (done < cnt) {
        int chunk = cnt - done; if (chunk > 32) chunk = 32;
        int myidx = 0;
        if (hl < chunk) {
            int gj = done + hl;
            myidx = (gj < cnt_b) ? (int)mybkt[gj] : n;
        }
        int j = 0;
        for (; j + 16 <= chunk; j += 16)
            edge_block<8>(myidx, j, sgbase, xbase, xr2, at2, c02, acc2, lden);
        if (j + 8 <= chunk) {
            edge_block<4>(myidx, j, sgbase, xbase, xr2, at2, c02, acc2, lden);
            j += 8;
        }
        if (j + 4 <= chunk) {
            edge_block<2>(myidx, j, sgbase, xbase, xr2, at2, c02, acc2, lden);
            j += 4;
        }
        for (; j < chunk; j += 2) {
            u32 off = (u32)__shfl(myidx, sgbase + j) << 8;
            uint4 q = *(const uint4*)(xbase + off);
            h2 v0 = U2H(q.x) + xr2[0];
            h2 v1 = U2H(q.y) + xr2[1];
            h2 v2 = U2H(q.z) + xr2[2];
            h2 v3 = U2H(q.w) + xr2[3];
            v0 = U2H(pkmax(H2Ub(v0), H2Ub(v0 * c02)));
            v1 = U2H(pkmax(H2Ub(v1), H2Ub(v1 * c02)));
            v2 = U2H(pkmax(H2Ub(v2), H2Ub(v2 * c02)));
            v3 = U2H(pkmax(H2Ub(v3), H2Ub(v3 * c02)));
            float s = fdot2f(v0, at2[0], 0.f);
            s = fdot2f(v1, at2[1], s);
            s = fdot2f(v2, at2[2], s);
            s = fdot2f(v3, at2[3], s);
            #pragma unroll
            for (int m = 4; m; m >>= 1) s += __shfl_xor(s, m);
            float p = (j + sgsel < chunk) ? exp2f(s) : 0.f;
            lden += p;
            _Float16 ph = (_Float16)p;
            h2 p2 = {ph, ph};
            acc2[0] += p2 * U2H(q.x);
            acc2[1] += p2 * U2H(q.y);
            acc2[2] += p2 * U2H(q.z);
            acc2[3] += p2 * U2H(q.w);
        }
        done += chunk;
    }

    #pragma unroll
    for (int i = 0; i < 4; i++) {
        u32 o = (u32)__shfl_xor((int)H2Ub(acc2[i]), 16);
        acc2[i] = acc2[i] + U2H(o);
    }
    lden += __shfl_xor(lden, 16);

    float rl = 1.f / fmaxf(lden, 1e-30f);
    if (!(l & 16)) {
        float4 b0 = *(const float4*)(bias + ch0);
        float4 b1 = *(const float4*)(bias + ch0 + 4);
        uint4 w;
        w.x = (u32)f2h((float)acc2[0][0] * rl + b0.x) |
              ((u32)f2h((float)acc2[0][1] * rl + b0.y) << 16);
        w.y = (u32)f2h((float)acc2[1][0] * rl + b0.z) |
              ((u32)f2h((float)acc2[1][1] * rl + b0.w) << 16);
        w.z = (u32)f2h((float)acc2[2][0] * rl + b1.x) |
              ((u32)f2h((float)acc2[2][1] * rl + b1.y) << 16);
        w.w = (u32)f2h((float)acc2[3][0] * rl + b1.z) |
              ((u32)f2h((float)acc2[3][1] * rl + b1.w) << 16);
        *(uint4*)&sAggU[half * 64 + g16 * 4] = w;
    }
    asm volatile("s_waitcnt lgkmcnt(0)" ::: "memory");   // same-wave DS visibility

    float h0 = bf[hl], h1 = bf[hl + 32];
    #pragma unroll 8
    for (int k4 = 0; k4 < 32; k4++) {
        uint4 wp = sWp[k4 * 32 + hl];
        uint2 ag = *(const uint2*)&sAggU[half * 64 + k4 * 2];
        h0 = fdot2f(U2H(ag.x), U2H(wp.x), h0);
        h0 = fdot2f(U2H(ag.y), U2H(wp.y), h0);
        h1 = fdot2f(U2H(ag.x), U2H(wp.z), h1);
        h1 = fdot2f(U2H(ag.y), U2H(wp.w), h1);
    }

    float s1r = h0 + h1, s2r = h0 * h0 + h1 * h1;
    #pragma unroll
    for (int m = 16; m; m >>= 1) { s1r += __shfl_xor(s1r, m); s2r += __shfl_xor(s2r, m); }
    float mu  = s1r * (1.f / 64.f);
    float var = s2r * (1.f / 64.f) - mu * mu;
    float rs  = rsqrtf(fmaxf(var, 0.f) + 1e-5f);
    if (active) {
        out[(size_t)n * DOUT + hl]      = (h0 - mu) * rs * gamma[hl]      + beta[hl];
        out[(size_t)n * DOUT + hl + 32] = (h1 - mu) * rs * gamma[hl + 32] + beta[hl + 32];
    }
}

// ---------------------------------------------------------------------------
extern "C" void kernel_launch(void* const* d_in, const int* in_sizes, int n_in,
                              void* d_out, int out_size, void* d_ws, size_t ws_size,
                              hipStream_t stream) {
    const float* X    = (const float*)d_in[0];
    const int*   E    = (const int*)d_in[1];
    const float* attr = (const float*)d_in[2];
    const float* Wl   = (const float*)d_in[3];
    const float* bl   = (const float*)d_in[4];
    const float* Wr   = (const float*)d_in[5];
    const float* br   = (const float*)d_in[6];
    const float* att  = (const float*)d_in[7];
    const float* bias = (const float*)d_in[8];
    const float* Wf   = (const float*)d_in[9];
    const float* bf   = (const float*)d_in[10];
    const float* gamma= (const float*)d_in[11];
    const float* beta = (const float*)d_in[12];
    float* out = (float*)d_out;

    const int N  = in_sizes[0] / DIN;
    const int NE = in_sizes[1] / 2;
    const int GB = (N + 63) / 64;

    char* ws = (char*)d_ws;
    int* count      = (int*)ws;               ws += (size_t)N * 4;
    u16* bucket     = (u16*)ws;               ws += (size_t)N * BCAP * 2;
    u16* xl_p       = (u16*)ws;               ws += (size_t)N * HD * 2;
    u16* xr_p       = (u16*)ws;               ws += (size_t)N * HD * 2;
    u16* WTl        = (u16*)ws;               ws += 128 * 128 * 2;
    u16* WTr        = (u16*)ws;               ws += 128 * 128 * 2;
    uint4* Wfp      = (uint4*)ws;             ws += 1024 * 16;

    k_prep<<<(N + 33792 + 255) / 256, 256, 0, stream>>>(
        Wl, Wr, Wf, WTl, WTr, Wfp, count, N);

    k_work<<<2 * GB, 256, 0, stream>>>(
        X, E, attr, WTl, bl, WTr, br, count, bucket, xl_p, xr_p, out, N, NE, GB);

    k_edge<<<(N + 7) / 8, 256, 0, stream>>>(
        xl_p, xr_p, att, bias, Wfp, bf, gamma, beta, count, bucket, out, N);
}